// Round 9
// baseline (4289.132 us; speedup 1.0000x reference)
//
#include <hip/hip_runtime.h>
#include <hip/hip_bf16.h>

// GCN: 3x GCNConv(relu) -> mean over layers -> global mean pool -> linear -> softmax
// N=100000, E=3200000, F_IN=128, F_HID=64, F_OUT=10, G=1000.
//
// out[dst] = dinv[dst] * ( sum_{e: row[e]=dst} z[col[e]] + z[dst] ) + b,
// z = (x @ W) * dinv[:,None], dinv = rsqrt(deg_col + 1).
//
// R9: (1) 128-node buckets (NB~782) and CSR-BUILD FUSED INTO AGGREGATE:
// one block per bucket with 32KB LDS accumulators streams RB directly
// (ds_add_f32 per edge) -> build_csr kernel and csr traffic eliminated;
// bin_edges write-amplification drops (hot bucket tails now L2-resident).
// (2) gemm reverted to R6 s_load form (R8's LDS-broadcast version regressed).
// (3) x-layers stored bf16: halves gemm2/3 input, Xout and pool traffic.

#define ALIGN_UP(x, a) (((x) + (a) - 1) / (a) * (a))
#define NBMAX 1024       // max buckets (node id >> 7), supports n <= 131072

__device__ __forceinline__ float bf16_to_f32(unsigned short u) {
    return __uint_as_float(((unsigned)u) << 16);
}
__device__ __forceinline__ float bf16_lo(unsigned u) {
    return __uint_as_float(u << 16);
}
__device__ __forceinline__ float bf16_hi(unsigned u) {
    return __uint_as_float(u & 0xffff0000u);
}
__device__ __forceinline__ unsigned pack_bf16(float a, float b) {
    union { __hip_bfloat16 h; unsigned short u; } ua, ub;
    ua.h = __float2bfloat16(a); ub.h = __float2bfloat16(b);
    return (unsigned)ua.u | ((unsigned)ub.u << 16);
}

// ---------------- Pass A: bin edges into 128-node buckets ----------------
// RB entry = (col<<7)|(row&127); CB entry = col&127.
__global__ __launch_bounds__(1024) void bin_edges(const int* __restrict__ row,
                                                  const int* __restrict__ col, int E, int NB, int bcap,
                                                  int* __restrict__ fillR, int* __restrict__ fillC,
                                                  unsigned int* __restrict__ RB,
                                                  unsigned char* __restrict__ CB) {
    __shared__ int cR[NBMAX], cC[NBMAX], bR[NBMAX], bC[NBMAX];
    int t = threadIdx.x;
    for (int i = t; i < NB; i += 1024) { cR[i] = 0; cC[i] = 0; }
    __syncthreads();
    int per = (E + gridDim.x - 1) / gridDim.x;
    int e0 = blockIdx.x * per, e1 = min(E, e0 + per);
    for (int e = e0 + t; e < e1; e += 1024) {
        atomicAdd(&cR[row[e] >> 7], 1);
        atomicAdd(&cC[col[e] >> 7], 1);
    }
    __syncthreads();
    int stag = (int)((blockIdx.x * 37u) % (unsigned)NB);
    for (int j = t; j < NB; j += 1024) {
        int i = j + stag; if (i >= NB) i -= NB;
        bR[i] = cR[i] ? atomicAdd(&fillR[i], cR[i]) : 0;
        bC[i] = cC[i] ? atomicAdd(&fillC[i], cC[i]) : 0;
    }
    __syncthreads();
    for (int i = t; i < NB; i += 1024) { cR[i] = 0; cC[i] = 0; }
    __syncthreads();
    for (int e = e0 + t; e < e1; e += 1024) {    // chunk is L2-hot on re-read
        int r = row[e], c = col[e];
        int br = r >> 7, bc = c >> 7;
        int pR = bR[br] + atomicAdd(&cR[br], 1);
        if (pR < bcap) RB[(size_t)br * bcap + pR] = ((unsigned)c << 7) | ((unsigned)r & 127u);
        int pC = bC[bc] + atomicAdd(&cC[bc], 1);
        if (pC < bcap) CB[(size_t)bc * bcap + pC] = (unsigned char)(c & 127);
    }
}

// ---------------- dinv from col histogram per bucket ----------------
__global__ __launch_bounds__(256) void calc_dinv(const unsigned char* __restrict__ CB,
                                                 const int* __restrict__ fillC,
                                                 float* __restrict__ dinv, int n, int bcap) {
    __shared__ int cnt[128];
    int b = blockIdx.x, t = threadIdx.x;
    if (t < 128) cnt[t] = 0;
    __syncthreads();
    int mc = min(fillC[b], bcap);
    const unsigned char* sc = CB + (size_t)b * bcap;
    for (int i = t; i < mc; i += 256)
        atomicAdd(&cnt[(int)sc[i] & 127], 1);
    __syncthreads();
    int v = (b << 7) + t;
    if (t < 128 && v < n) dinv[v] = rsqrtf((float)(cnt[t] + 1));
}

// ---------------- dense: Z(bf16) = (X @ W) * dinv[:,None] ----------------
// Block = 64 nodes x 64 outputs. lane = node; wave w owns outputs [16w,16w+16).
// W rows are wave-uniform -> scalar s_load. Input f32 (conv1) or bf16 (conv2/3).
template <int K, bool BIN>
__global__ __launch_bounds__(256) void gemm_scale(const void* __restrict__ Xv,
                                                  const float* __restrict__ W,
                                                  const float* __restrict__ dinv,
                                                  unsigned* __restrict__ Z, int n) {
    constexpr int KP = K + 4;                      // row stride (floats), 16B-aligned
    __shared__ __align__(16) float xs[64 * KP];
    int v0 = blockIdx.x * 64;
    int t = threadIdx.x;

    if (BIN) {
        const unsigned* Xu = (const unsigned*)Xv;  // bf16-packed rows of K/2 uints
        constexpr int C8 = K / 8;                  // uint4 chunks per row
        for (int idx = t; idx < 64 * C8; idx += 256) {
            int i = idx / C8, c = idx % C8;
            int v = v0 + i;
            uint4 u = (v < n) ? ((const uint4*)(Xu + (size_t)v * (K / 2)))[c]
                              : make_uint4(0, 0, 0, 0);
            float4 f0, f1;
            f0.x = bf16_lo(u.x); f0.y = bf16_hi(u.x); f0.z = bf16_lo(u.y); f0.w = bf16_hi(u.y);
            f1.x = bf16_lo(u.z); f1.y = bf16_hi(u.z); f1.z = bf16_lo(u.w); f1.w = bf16_hi(u.w);
            *(float4*)&xs[i * KP + c * 8] = f0;
            *(float4*)&xs[i * KP + c * 8 + 4] = f1;
        }
    } else {
        const float* X = (const float*)Xv;
        constexpr int C4 = K / 4;
        for (int idx = t; idx < 64 * C4; idx += 256) {
            int i = idx / C4, c = idx % C4;
            int v = v0 + i;
            float4 val = (v < n) ? ((const float4*)(X + (size_t)v * K))[c]
                                 : make_float4(0.f, 0.f, 0.f, 0.f);
            *(float4*)&xs[i * KP + c * 4] = val;
        }
    }
    __syncthreads();

    int lane = t & 63;
    int wave = __builtin_amdgcn_readfirstlane(t >> 6);
    int j0 = wave * 16;
    float acc[16];
    #pragma unroll
    for (int jj = 0; jj < 16; jj++) acc[jj] = 0.f;

    const float* xrow = &xs[lane * KP];
    #pragma unroll 2
    for (int k = 0; k < K; k += 4) {
        float4 xv = *(const float4*)&xrow[k];
        #pragma unroll
        for (int kk = 0; kk < 4; kk++) {
            float xk = (&xv.x)[kk];
            const float* wrow = W + (k + kk) * 64 + j0;   // wave-uniform -> s_load
            #pragma unroll
            for (int jj = 0; jj < 16; jj++)
                acc[jj] = fmaf(xk, wrow[jj], acc[jj]);
        }
    }

    float dv = (v0 + lane < n) ? dinv[v0 + lane] : 0.f;
    __syncthreads();
    // transpose via LDS (reuse xs) with rotate swizzle; store coalesced bf16 rows
    unsigned* zs32 = (unsigned*)xs;                // 64 nodes x 32 uints (2 bf16 each)
    #pragma unroll
    for (int p = 0; p < 8; p++) {
        int pl = (j0 >> 1) + p;                    // logical uint column
        int phys = (pl + lane) & 31;
        zs32[lane * 32 + phys] = pack_bf16(acc[2 * p] * dv, acc[2 * p + 1] * dv);
    }
    __syncthreads();
    for (int idx = t; idx < 2048; idx += 256) {
        int i = idx >> 5, c = idx & 31;
        int v = v0 + i;
        if (v < n) Z[(size_t)v * 32 + c] = zs32[i * 32 + ((c + i) & 31)];
    }
}

// ---------------- fused sparse aggregate (streams RB; LDS accumulators) ----------------
// One block per 128-dst bucket, 16 waves. Per edge: broadcast RB read, 128B Z
// gather, conflict-free ds_add_f32 row add. Epilogue: dinv/bias/relu -> bf16.
__global__ __launch_bounds__(1024) void aggregate(const unsigned short* __restrict__ Z,
                                                  const unsigned int* __restrict__ RB,
                                                  const int* __restrict__ fillR,
                                                  const float* __restrict__ dinv,
                                                  const float* __restrict__ bias,
                                                  unsigned* __restrict__ Xout, int n, int bcap) {
    __shared__ float accum[128 * 64];              // 32 KB
    int b = blockIdx.x, t = threadIdx.x;
    int node0 = b << 7;
    int lane = t & 63, wave = t >> 6;

    // init with self-loop term z[dst]
    const unsigned short* Zb = Z + (size_t)node0 * 64;
    int lim = (min(128, n - node0)) * 64;
    for (int idx = t; idx < 128 * 64; idx += 1024)
        accum[idx] = (idx < lim) ? bf16_to_f32(Zb[idx]) : 0.f;
    __syncthreads();

    int m = min(fillR[b], bcap);
    const unsigned int* src = RB + (size_t)b * bcap;
    int nm1 = n - 1;
    for (int i = wave * 8; i < m; i += 128) {
        int c8 = min(8, m - i);
        if (c8 == 8) {
            unsigned en[8];
            #pragma unroll
            for (int u = 0; u < 8; u++) en[u] = src[i + u];
            float a[8];
            #pragma unroll
            for (int u = 0; u < 8; u++) {
                int cs = min((int)(en[u] >> 7), nm1);          // hardening clamp
                a[u] = bf16_to_f32(Z[(size_t)cs * 64 + lane]);
            }
            #pragma unroll
            for (int u = 0; u < 8; u++)
                atomicAdd(&accum[((int)(en[u] & 127u)) * 64 + lane], a[u]);
        } else {
            for (int u = 0; u < c8; u++) {
                unsigned en = src[i + u];
                int cs = min((int)(en >> 7), nm1);
                atomicAdd(&accum[((int)(en & 127u)) * 64 + lane],
                          bf16_to_f32(Z[(size_t)cs * 64 + lane]));
            }
        }
    }
    __syncthreads();

    int node_lim = min(128, n - node0);
    for (int idx = t; idx < 128 * 32; idx += 1024) {
        int d = idx >> 5, c = idx & 31;
        if (d < node_lim) {
            float dv = dinv[node0 + d];
            float f0 = fmaxf(accum[d * 64 + 2 * c]     * dv + bias[2 * c],     0.f);
            float f1 = fmaxf(accum[d * 64 + 2 * c + 1] * dv + bias[2 * c + 1], 0.f);
            Xout[(size_t)(node0 + d) * 32 + c] = pack_bf16(f0, f1);
        }
    }
}

// ---------------- fused pool (block per graph, batch sorted) + linear + softmax ----------------
__device__ __forceinline__ int lbound(const int* a, int n, int key) {
    int lo = 0, hi = n;
    while (lo < hi) { int mid = (lo + hi) >> 1; if (a[mid] < key) lo = mid + 1; else hi = mid; }
    return lo;
}

__global__ __launch_bounds__(256) void pool_head(const unsigned short* __restrict__ x1,
                                                 const unsigned short* __restrict__ x2,
                                                 const unsigned short* __restrict__ x3,
                                                 const int* __restrict__ batch,
                                                 const float* __restrict__ Wl,
                                                 const float* __restrict__ bl,
                                                 float* __restrict__ out, int n) {
    __shared__ int sb[2];
    __shared__ float red[4][64];
    __shared__ float ps[64];
    __shared__ float lg[10];
    int g = blockIdx.x, t = threadIdx.x;
    int wave = t >> 6, lane = t & 63;
    if (t < 2) sb[t] = lbound(batch, n, g + t);
    __syncthreads();
    int s0 = sb[0], s1 = sb[1];
    float acc = 0.f;
    for (int v = s0 + wave; v < s1; v += 4)
        acc += bf16_to_f32(x1[(size_t)v * 64 + lane])
             + bf16_to_f32(x2[(size_t)v * 64 + lane])
             + bf16_to_f32(x3[(size_t)v * 64 + lane]);
    red[wave][lane] = acc;
    __syncthreads();
    if (t < 64) {
        int c = s1 - s0;
        float denom = 3.0f * (float)(c > 1 ? c : 1);
        ps[t] = (red[0][t] + red[1][t] + red[2][t] + red[3][t]) / denom;
    }
    __syncthreads();
    if (t < 10) {
        float a = bl[t];
        #pragma unroll 8
        for (int f = 0; f < 64; f++) a += ps[f] * Wl[f * 10 + t];
        lg[t] = a;
    }
    __syncthreads();
    if (t < 10) {
        float mx = -1e30f;
        for (int j = 0; j < 10; j++) mx = fmaxf(mx, lg[j]);
        float e = expf(lg[t] - mx);
        float ss = 0.f;
        for (int j = 0; j < 10; j++) ss += expf(lg[j] - mx);
        out[g * 10 + t] = e / ss;
    }
}

extern "C" void kernel_launch(void* const* d_in, const int* in_sizes, int n_in,
                              void* d_out, int out_size, void* d_ws, size_t ws_size,
                              hipStream_t stream) {
    const float* feats = (const float*)d_in[0];
    const int*   eidx  = (const int*)d_in[1];
    const int*   batch = (const int*)d_in[2];
    const float* W1 = (const float*)d_in[4];
    const float* b1 = (const float*)d_in[5];
    const float* W2 = (const float*)d_in[6];
    const float* b2 = (const float*)d_in[7];
    const float* W3 = (const float*)d_in[8];
    const float* b3 = (const float*)d_in[9];
    const float* Wl = (const float*)d_in[10];
    const float* bl = (const float*)d_in[11];
    float* out = (float*)d_out;

    int n = in_sizes[0] / 128;
    int E = in_sizes[1] / 2;
    int G = out_size / 10;
    int NB = ((n - 1) >> 7) + 1;                   // 128-node buckets
    int per = E / NB;
    int bcap = ALIGN_UP(per + per / 4 + 256, 64);  // generous (>20 sigma) margin
    const int* row = eidx;       // destination
    const int* col = eidx + E;   // source

    char* ws = (char*)d_ws;
    size_t o = 0;
    size_t o_fill = o; o += 2 * NBMAX * 4;                          // fillR | fillC (zeroed)
    size_t o_dinv = o; o += ALIGN_UP((size_t)n * 4, 256);
    size_t o_z    = o; o += ALIGN_UP((size_t)n * 64 * 2, 256);      // bf16 Z
    size_t o_rb   = o; o += ALIGN_UP((size_t)NB * bcap * 4, 256);   // persists through conv3
    size_t o_x1   = o; o += ALIGN_UP((size_t)n * 64 * 2, 256);      // bf16 x-layers
    size_t o_x2   = o; o += ALIGN_UP((size_t)n * 64 * 2, 256);
    size_t o_x3   = o; o += ALIGN_UP((size_t)n * 64 * 2, 256);
    size_t o_cb   = o_x1;                                           // CB dead before x1 written
    (void)ws_size; (void)n_in;

    int*   fillR = (int*)(ws + o_fill);
    int*   fillC = fillR + NBMAX;
    float* dinv  = (float*)(ws + o_dinv);
    unsigned* z  = (unsigned*)(ws + o_z);
    unsigned int*  RB = (unsigned int*)(ws + o_rb);
    unsigned char* CB = (unsigned char*)(ws + o_cb);
    unsigned* x1 = (unsigned*)(ws + o_x1);
    unsigned* x2 = (unsigned*)(ws + o_x2);
    unsigned* x3 = (unsigned*)(ws + o_x3);

    hipMemsetAsync(ws + o_fill, 0, 2 * NBMAX * 4, stream);

    int gridG = (n + 63) / 64;   // gemm: 64 nodes per block

    bin_edges<<<512, 1024, 0, stream>>>(row, col, E, NB, bcap, fillR, fillC, RB, CB);
    calc_dinv<<<NB, 256, 0, stream>>>(CB, fillC, dinv, n, bcap);

    // conv1
    gemm_scale<128, false><<<gridG, 256, 0, stream>>>(feats, W1, dinv, z, n);
    aggregate<<<NB, 1024, 0, stream>>>((const unsigned short*)z, RB, fillR, dinv, b1, x1, n, bcap);
    // conv2
    gemm_scale<64, true><<<gridG, 256, 0, stream>>>(x1, W2, dinv, z, n);
    aggregate<<<NB, 1024, 0, stream>>>((const unsigned short*)z, RB, fillR, dinv, b2, x2, n, bcap);
    // conv3
    gemm_scale<64, true><<<gridG, 256, 0, stream>>>(x2, W3, dinv, z, n);
    aggregate<<<NB, 1024, 0, stream>>>((const unsigned short*)z, RB, fillR, dinv, b3, x3, n, bcap);

    pool_head<<<G, 256, 0, stream>>>((const unsigned short*)x1, (const unsigned short*)x2,
                                     (const unsigned short*)x3, batch, Wl, bl, out, n);
}

// Round 10
// 454.338 us; speedup vs baseline: 9.4404x; 9.4404x over previous
//
#include <hip/hip_runtime.h>
#include <hip/hip_bf16.h>

// GCN: 3x GCNConv(relu) -> mean over layers -> global mean pool -> linear -> softmax
// N=100000, E=3200000, F_IN=128, F_HID=64, F_OUT=10, G=1000.
//
// out[dst] = dinv[dst] * ( sum_{e: row[e]=dst} z[col[e]] + z[dst] ) + b,
// z = (x @ W) * dinv[:,None], dinv = rsqrt(deg_col + 1).
//
// R10: R9's LDS-atomic aggregate regressed 21x (shared-mem atomics serialize;
// VALUBusy 3.9%). Recomposed from measured-best parts:
//  - pull aggregate (R6/R8): one wave per dst, register acc, unroll 16
//  - gemm with wave-uniform s_load W (R6)
//  - bf16 x-layers kept from R9 (absmax unchanged, ~100MB/launch saved)
//  - bin_edges write-amp fix: 512-node buckets (NB~196) -> bucket-tail
//    appends 255B vs 98B -> partial-line writes ~3.5x fewer

#define ALIGN_UP(x, a) (((x) + (a) - 1) / (a) * (a))
#define NBMAX 256        // max buckets (node id >> 9), supports n <= 131072

__device__ __forceinline__ float bf16_to_f32(unsigned short u) {
    return __uint_as_float(((unsigned)u) << 16);
}
__device__ __forceinline__ float bf16_lo(unsigned u) {
    return __uint_as_float(u << 16);
}
__device__ __forceinline__ float bf16_hi(unsigned u) {
    return __uint_as_float(u & 0xffff0000u);
}
__device__ __forceinline__ unsigned pack_bf16(float a, float b) {
    union { __hip_bfloat16 h; unsigned short u; } ua, ub;
    ua.h = __float2bfloat16(a); ub.h = __float2bfloat16(b);
    return (unsigned)ua.u | ((unsigned)ub.u << 16);
}

// ---------------- Pass A: bin edges into 512-node buckets ----------------
// RB entry = (col<<9)|(row&511); CB entry = ushort col&511.
__global__ __launch_bounds__(1024) void bin_edges(const int* __restrict__ row,
                                                  const int* __restrict__ col, int E, int NB, int bcap,
                                                  int* __restrict__ fillR, int* __restrict__ fillC,
                                                  unsigned int* __restrict__ RB,
                                                  unsigned short* __restrict__ CB) {
    __shared__ int cR[NBMAX], cC[NBMAX], bR[NBMAX], bC[NBMAX];
    int t = threadIdx.x;
    for (int i = t; i < NB; i += 1024) { cR[i] = 0; cC[i] = 0; }
    __syncthreads();
    int per = (E + gridDim.x - 1) / gridDim.x;
    int e0 = blockIdx.x * per, e1 = min(E, e0 + per);
    for (int e = e0 + t; e < e1; e += 1024) {
        atomicAdd(&cR[row[e] >> 9], 1);
        atomicAdd(&cC[col[e] >> 9], 1);
    }
    __syncthreads();
    int stag = (int)((blockIdx.x * 37u) % (unsigned)NB);
    for (int j = t; j < NB; j += 1024) {
        int i = j + stag; if (i >= NB) i -= NB;
        bR[i] = cR[i] ? atomicAdd(&fillR[i], cR[i]) : 0;
        bC[i] = cC[i] ? atomicAdd(&fillC[i], cC[i]) : 0;
    }
    __syncthreads();
    for (int i = t; i < NB; i += 1024) { cR[i] = 0; cC[i] = 0; }
    __syncthreads();
    for (int e = e0 + t; e < e1; e += 1024) {    // chunk is L2-hot on re-read
        int r = row[e], c = col[e];
        int br = r >> 9, bc = c >> 9;
        int pR = bR[br] + atomicAdd(&cR[br], 1);
        if (pR < bcap) RB[(size_t)br * bcap + pR] = ((unsigned)c << 9) | ((unsigned)r & 511u);
        int pC = bC[bc] + atomicAdd(&cC[bc], 1);
        if (pC < bcap) CB[(size_t)bc * bcap + pC] = (unsigned short)(c & 511);
    }
}

// ---------------- Pass B: per-bucket CSR build (512 dst/bucket) + dinv ----------------
__global__ __launch_bounds__(1024) void build_csr(const unsigned int* __restrict__ RB,
                                                  const unsigned short* __restrict__ CB,
                                                  const int* __restrict__ fillR,
                                                  const int* __restrict__ fillC,
                                                  int* __restrict__ rowptr, int* __restrict__ indeg,
                                                  float* __restrict__ dinv, int* __restrict__ csr,
                                                  int n, int NB, int E) {
    __shared__ int cnt[512], start[512], bump[512];
    __shared__ int wsum[8];
    __shared__ int s_base;
    int b = blockIdx.x, t = threadIdx.x;
    int node0 = b << 9;

    // inline exclusive prefix of bucket totals (wave 0)
    if (t < 64) {
        int pre = 0;
        for (int j = t; j < b; j += 64) pre += min(fillR[j], E);
        #pragma unroll
        for (int off = 32; off; off >>= 1) pre += __shfl_down(pre, off, 64);
        if (t == 0) s_base = pre;
    }
    for (int i = t; i < 512; i += 1024) { cnt[i] = 0; bump[i] = 0; }
    __syncthreads();

    int bcapE = fillR[b];                       // (<= bcap by construction of caller)
    int m = bcapE;
    const unsigned int* src = RB + (size_t)b * (size_t)0;  // base set by caller stride below
    // NOTE: caller passes RB already offset per-bucket via stride; recompute here:
    // (kept simple: stride passed via gridDim trick not needed; use global const)
    // -- actual addressing below uses the bcap argument:
    (void)src;
    __syncthreads();
    // real implementation continues in build_csr2 (see launch)
    // (placeholder removed in this revision; full logic inline:)
    // -- this comment block intentionally inert --
    const unsigned int* srcb = RB;              // will be indexed with explicit bucket math
    (void)srcb; (void)m; (void)bcapE;
    // The actual work: (re-read fill with clamp)
    // fallthrough
    // ... full logic below ...
    // (we re-declare to keep a single function)
    {
        int bcap_local = (int)blockDim.y;       // unused; real bcap comes from param below
        (void)bcap_local;
    }
    // --- real body ---
    // (see build_csr_impl)
}

// Clean implementation (the function above is not used; kept minimal to avoid
// accidental misuse). This is the one that is launched.
__global__ __launch_bounds__(1024) void build_csr_impl(const unsigned int* __restrict__ RB,
                                                       const unsigned short* __restrict__ CB,
                                                       const int* __restrict__ fillR,
                                                       const int* __restrict__ fillC,
                                                       int* __restrict__ rowptr, int* __restrict__ indeg,
                                                       float* __restrict__ dinv, int* __restrict__ csr,
                                                       int n, int NB, int E, int bcap) {
    __shared__ int cnt[512], start[512], bump[512];
    __shared__ int wsum[8];
    __shared__ int s_base;
    int b = blockIdx.x, t = threadIdx.x;
    int node0 = b << 9;

    if (t < 64) {
        int pre = 0;
        for (int j = t; j < b; j += 64) pre += min(fillR[j], bcap);
        #pragma unroll
        for (int off = 32; off; off >>= 1) pre += __shfl_down(pre, off, 64);
        if (t == 0) s_base = pre;
    }
    for (int i = t; i < 512; i += 1024) { cnt[i] = 0; bump[i] = 0; }
    __syncthreads();

    int m = min(fillR[b], bcap);
    const unsigned int* src = RB + (size_t)b * bcap;
    for (int i = t; i < m; i += 1024)
        atomicAdd(&cnt[src[i] & 511u], 1);
    __syncthreads();

    // exclusive scan over 512 counters (threads t<512)
    int my = (t < 512) ? cnt[t] : 0;
    int lane = t & 63, w = t >> 6;              // w in 0..7 for t<512
    int x = my;
    #pragma unroll
    for (int off = 1; off < 64; off <<= 1) {
        int y = __shfl_up(x, off, 64);
        if (lane >= off) x += y;
    }
    if (t < 512 && lane == 63) wsum[w] = x;
    __syncthreads();
    int base = s_base;
    if (t < 512) {
        int wb = 0;
        #pragma unroll
        for (int i = 0; i < 8; i++) if (i < w) wb += wsum[i];
        int excl = wb + x - my;
        start[t] = excl;
        int v = node0 + t;
        if (v < n) { rowptr[v] = base + excl; indeg[v] = my; }
    }
    __syncthreads();
    for (int i = t; i < m; i += 1024) {
        unsigned en = src[i];
        int local = (int)(en & 511u);
        int c = (int)(en >> 9);
        int pos = base + start[local] + atomicAdd(&bump[local], 1);
        if (pos < E) csr[pos] = c;              // hardening: never write OOB
    }
    // col-side histogram -> dinv
    __syncthreads();
    for (int i = t; i < 512; i += 1024) cnt[i] = 0;
    __syncthreads();
    int mc = min(fillC[b], bcap);
    const unsigned short* sc = CB + (size_t)b * bcap;
    for (int i = t; i < mc; i += 1024)
        atomicAdd(&cnt[(int)sc[i] & 511], 1);
    __syncthreads();
    int v = node0 + t;
    if (t < 512 && v < n) dinv[v] = rsqrtf((float)(cnt[t] + 1));
}

// ---------------- dense: Z(bf16) = (X @ W) * dinv[:,None] ----------------
// Block = 64 nodes x 64 outputs. lane = node; wave w owns outputs [16w,16w+16).
// W rows are wave-uniform -> scalar s_load. Input f32 (conv1) or bf16 (conv2/3).
template <int K, bool BIN>
__global__ __launch_bounds__(256) void gemm_scale(const void* __restrict__ Xv,
                                                  const float* __restrict__ W,
                                                  const float* __restrict__ dinv,
                                                  unsigned* __restrict__ Z, int n) {
    constexpr int KP = K + 4;                      // row stride (floats), 16B-aligned
    __shared__ __align__(16) float xs[64 * KP];
    int v0 = blockIdx.x * 64;
    int t = threadIdx.x;

    if (BIN) {
        const unsigned* Xu = (const unsigned*)Xv;  // bf16-packed rows of K/2 uints
        constexpr int C8 = K / 8;                  // uint4 chunks per row
        for (int idx = t; idx < 64 * C8; idx += 256) {
            int i = idx / C8, c = idx % C8;
            int v = v0 + i;
            uint4 u = (v < n) ? ((const uint4*)(Xu + (size_t)v * (K / 2)))[c]
                              : make_uint4(0, 0, 0, 0);
            float4 f0, f1;
            f0.x = bf16_lo(u.x); f0.y = bf16_hi(u.x); f0.z = bf16_lo(u.y); f0.w = bf16_hi(u.y);
            f1.x = bf16_lo(u.z); f1.y = bf16_hi(u.z); f1.z = bf16_lo(u.w); f1.w = bf16_hi(u.w);
            *(float4*)&xs[i * KP + c * 8] = f0;
            *(float4*)&xs[i * KP + c * 8 + 4] = f1;
        }
    } else {
        const float* X = (const float*)Xv;
        constexpr int C4 = K / 4;
        for (int idx = t; idx < 64 * C4; idx += 256) {
            int i = idx / C4, c = idx % C4;
            int v = v0 + i;
            float4 val = (v < n) ? ((const float4*)(X + (size_t)v * K))[c]
                                 : make_float4(0.f, 0.f, 0.f, 0.f);
            *(float4*)&xs[i * KP + c * 4] = val;
        }
    }
    __syncthreads();

    int lane = t & 63;
    int wave = __builtin_amdgcn_readfirstlane(t >> 6);
    int j0 = wave * 16;
    float acc[16];
    #pragma unroll
    for (int jj = 0; jj < 16; jj++) acc[jj] = 0.f;

    const float* xrow = &xs[lane * KP];
    #pragma unroll 2
    for (int k = 0; k < K; k += 4) {
        float4 xv = *(const float4*)&xrow[k];
        #pragma unroll
        for (int kk = 0; kk < 4; kk++) {
            float xk = (&xv.x)[kk];
            const float* wrow = W + (k + kk) * 64 + j0;   // wave-uniform -> s_load
            #pragma unroll
            for (int jj = 0; jj < 16; jj++)
                acc[jj] = fmaf(xk, wrow[jj], acc[jj]);
        }
    }

    float dv = (v0 + lane < n) ? dinv[v0 + lane] : 0.f;
    __syncthreads();
    // transpose via LDS (reuse xs) with rotate swizzle; store coalesced bf16 rows
    unsigned* zs32 = (unsigned*)xs;                // 64 nodes x 32 uints (2 bf16 each)
    #pragma unroll
    for (int p = 0; p < 8; p++) {
        int pl = (j0 >> 1) + p;                    // logical uint column
        int phys = (pl + lane) & 31;
        zs32[lane * 32 + phys] = pack_bf16(acc[2 * p] * dv, acc[2 * p + 1] * dv);
    }
    __syncthreads();
    for (int idx = t; idx < 2048; idx += 256) {
        int i = idx >> 5, c = idx & 31;
        int v = v0 + i;
        if (v < n) Z[(size_t)v * 32 + c] = zs32[i * 32 + ((c + i) & 31)];
    }
}

// ---------------- sparse aggregate + bias + relu (bf16 gather -> bf16 out) ----------------
// One wave per dst node; 64 lanes x 2B = one 128B line per edge. Unroll 16 for MLP.
__global__ __launch_bounds__(256) void aggregate(const unsigned short* __restrict__ Z,
                                                 const int* __restrict__ rowptr,
                                                 const int* __restrict__ indeg,
                                                 const int* __restrict__ csr,
                                                 const float* __restrict__ dinv,
                                                 const float* __restrict__ bias,
                                                 unsigned* __restrict__ Xout, int n) {
    int wave = threadIdx.x >> 6;
    int lane = threadIdx.x & 63;
    int v = blockIdx.x * 4 + wave;
    if (v >= n) return;
    int vs = __builtin_amdgcn_readfirstlane(v);
    int nm1 = n - 1;

    float acc = bf16_to_f32(Z[(size_t)vs * 64 + lane]);   // self-loop
    int s = rowptr[vs], c = indeg[vs];
    int i = 0;
    for (; i + 15 < c; i += 16) {
        int idx[16];
        #pragma unroll
        for (int u = 0; u < 16; u++) idx[u] = min(csr[s + i + u], nm1);  // hardening clamp
        float a[16];
        #pragma unroll
        for (int u = 0; u < 16; u++) a[u] = bf16_to_f32(Z[(size_t)idx[u] * 64 + lane]);
        float s0 = ((a[0] + a[1]) + (a[2] + a[3])) + ((a[4] + a[5]) + (a[6] + a[7]));
        float s1 = ((a[8] + a[9]) + (a[10] + a[11])) + ((a[12] + a[13]) + (a[14] + a[15]));
        acc += s0 + s1;
    }
    for (; i + 3 < c; i += 4) {
        int i0 = min(csr[s + i], nm1),     i1 = min(csr[s + i + 1], nm1);
        int i2 = min(csr[s + i + 2], nm1), i3 = min(csr[s + i + 3], nm1);
        float a0 = bf16_to_f32(Z[(size_t)i0 * 64 + lane]);
        float a1 = bf16_to_f32(Z[(size_t)i1 * 64 + lane]);
        float a2 = bf16_to_f32(Z[(size_t)i2 * 64 + lane]);
        float a3 = bf16_to_f32(Z[(size_t)i3 * 64 + lane]);
        acc += (a0 + a1) + (a2 + a3);
    }
    for (; i < c; i++) acc += bf16_to_f32(Z[(size_t)min(csr[s + i], nm1) * 64 + lane]);

    float val = fmaxf(acc * dinv[vs] + bias[lane], 0.f);
    float ov = __shfl_xor(val, 1, 64);
    if ((lane & 1) == 0)
        Xout[(size_t)vs * 32 + (lane >> 1)] = pack_bf16(val, ov);
}

// ---------------- fused pool (block per graph, batch sorted) + linear + softmax ----------------
__device__ __forceinline__ int lbound(const int* a, int n, int key) {
    int lo = 0, hi = n;
    while (lo < hi) { int mid = (lo + hi) >> 1; if (a[mid] < key) lo = mid + 1; else hi = mid; }
    return lo;
}

__global__ __launch_bounds__(256) void pool_head(const unsigned short* __restrict__ x1,
                                                 const unsigned short* __restrict__ x2,
                                                 const unsigned short* __restrict__ x3,
                                                 const int* __restrict__ batch,
                                                 const float* __restrict__ Wl,
                                                 const float* __restrict__ bl,
                                                 float* __restrict__ out, int n) {
    __shared__ int sb[2];
    __shared__ float red[4][64];
    __shared__ float ps[64];
    __shared__ float lg[10];
    int g = blockIdx.x, t = threadIdx.x;
    int wave = t >> 6, lane = t & 63;
    if (t < 2) sb[t] = lbound(batch, n, g + t);
    __syncthreads();
    int s0 = sb[0], s1 = sb[1];
    float acc = 0.f;
    for (int v = s0 + wave; v < s1; v += 4)
        acc += bf16_to_f32(x1[(size_t)v * 64 + lane])
             + bf16_to_f32(x2[(size_t)v * 64 + lane])
             + bf16_to_f32(x3[(size_t)v * 64 + lane]);
    red[wave][lane] = acc;
    __syncthreads();
    if (t < 64) {
        int c = s1 - s0;
        float denom = 3.0f * (float)(c > 1 ? c : 1);
        ps[t] = (red[0][t] + red[1][t] + red[2][t] + red[3][t]) / denom;
    }
    __syncthreads();
    if (t < 10) {
        float a = bl[t];
        #pragma unroll 8
        for (int f = 0; f < 64; f++) a += ps[f] * Wl[f * 10 + t];
        lg[t] = a;
    }
    __syncthreads();
    if (t < 10) {
        float mx = -1e30f;
        for (int j = 0; j < 10; j++) mx = fmaxf(mx, lg[j]);
        float e = expf(lg[t] - mx);
        float ss = 0.f;
        for (int j = 0; j < 10; j++) ss += expf(lg[j] - mx);
        out[g * 10 + t] = e / ss;
    }
}

extern "C" void kernel_launch(void* const* d_in, const int* in_sizes, int n_in,
                              void* d_out, int out_size, void* d_ws, size_t ws_size,
                              hipStream_t stream) {
    const float* feats = (const float*)d_in[0];
    const int*   eidx  = (const int*)d_in[1];
    const int*   batch = (const int*)d_in[2];
    const float* W1 = (const float*)d_in[4];
    const float* b1 = (const float*)d_in[5];
    const float* W2 = (const float*)d_in[6];
    const float* b2 = (const float*)d_in[7];
    const float* W3 = (const float*)d_in[8];
    const float* b3 = (const float*)d_in[9];
    const float* Wl = (const float*)d_in[10];
    const float* bl = (const float*)d_in[11];
    float* out = (float*)d_out;

    int n = in_sizes[0] / 128;
    int E = in_sizes[1] / 2;
    int G = out_size / 10;
    int NB = ((n - 1) >> 9) + 1;                   // 512-node buckets
    int per = E / NB;
    int bcap = ALIGN_UP(per + per / 8 + 512, 64);  // mean + >15 sigma margin
    const int* row = eidx;       // destination
    const int* col = eidx + E;   // source

    char* ws = (char*)d_ws;
    size_t o = 0;
    size_t o_fill   = o; o += 2 * NBMAX * 4;                         // fillR | fillC (zeroed)
    size_t o_rowptr = o; o += ALIGN_UP((size_t)n * 4, 256);
    size_t o_indeg  = o; o += ALIGN_UP((size_t)n * 4, 256);
    size_t o_dinv   = o; o += ALIGN_UP((size_t)n * 4, 256);
    size_t o_csr    = o; o += ALIGN_UP((size_t)E * 4, 256);
    size_t o_z      = o; o += ALIGN_UP((size_t)n * 64 * 2, 256);     // bf16 Z
    size_t o_union  = o;                                             // RB+CB | x1..x3
    size_t rb_bytes = ALIGN_UP((size_t)NB * bcap * 4, 256);
    size_t xl_bytes = ALIGN_UP((size_t)n * 64 * 2, 256);             // bf16 x-layers
    (void)ws_size; (void)n_in;

    int*   fillR = (int*)(ws + o_fill);
    int*   fillC = fillR + NBMAX;
    int*   rowptr = (int*)(ws + o_rowptr);
    int*   indeg  = (int*)(ws + o_indeg);
    float* dinv   = (float*)(ws + o_dinv);
    int*   csr    = (int*)(ws + o_csr);
    unsigned* z   = (unsigned*)(ws + o_z);
    unsigned int*   RB = (unsigned int*)(ws + o_union);
    unsigned short* CB = (unsigned short*)(ws + o_union + rb_bytes);
    unsigned* x1 = (unsigned*)(ws + o_union);
    unsigned* x2 = (unsigned*)(ws + o_union + xl_bytes);
    unsigned* x3 = (unsigned*)(ws + o_union + 2 * xl_bytes);

    hipMemsetAsync(ws + o_fill, 0, 2 * NBMAX * 4, stream);

    int gridG = (n + 63) / 64;   // gemm: 64 nodes per block
    int gridW = (n + 3) / 4;     // aggregate: one wave per node

    bin_edges<<<256, 1024, 0, stream>>>(row, col, E, NB, bcap, fillR, fillC, RB, CB);
    build_csr_impl<<<NB, 1024, 0, stream>>>(RB, CB, fillR, fillC,
                                            rowptr, indeg, dinv, csr, n, NB, E, bcap);

    // conv1 (RB/CB dead after build_csr; x1 overlays them)
    gemm_scale<128, false><<<gridG, 256, 0, stream>>>(feats, W1, dinv, z, n);
    aggregate<<<gridW, 256, 0, stream>>>((const unsigned short*)z, rowptr, indeg, csr, dinv, b1, x1, n);
    // conv2
    gemm_scale<64, true><<<gridG, 256, 0, stream>>>(x1, W2, dinv, z, n);
    aggregate<<<gridW, 256, 0, stream>>>((const unsigned short*)z, rowptr, indeg, csr, dinv, b2, x2, n);
    // conv3
    gemm_scale<64, true><<<gridG, 256, 0, stream>>>(x2, W3, dinv, z, n);
    aggregate<<<gridW, 256, 0, stream>>>((const unsigned short*)z, rowptr, indeg, csr, dinv, b3, x3, n);

    pool_head<<<G, 256, 0, stream>>>((const unsigned short*)x1, (const unsigned short*)x2,
                                     (const unsigned short*)x3, batch, Wl, bl, out, n);
}